// Round 1
// baseline (516.775 us; speedup 1.0000x reference)
//
#include <hip/hip_runtime.h>

// EdgeModel: out = (relu(x@W1+b1))@W2 + b2 + x, x = [src|dest|ea|u[batch]] per edge
// E=1e6, dims all 128. bf16 MFMA (16x16x32), fp32 accumulate, fp32 residual.

#define E_TOTAL   1000000
#define NUM_TILES (E_TOTAL / 64)   // 15625, exact

typedef __attribute__((ext_vector_type(8))) __bf16 bf16x8;
typedef __attribute__((ext_vector_type(4))) float  f32x4;

__device__ inline bf16x8 cvt8(const float* __restrict__ p) {
    f32x4 v0 = *(const f32x4*)p;
    f32x4 v1 = *(const f32x4*)(p + 4);
    bf16x8 r;
    r[0] = (__bf16)v0[0]; r[1] = (__bf16)v0[1];
    r[2] = (__bf16)v0[2]; r[3] = (__bf16)v0[3];
    r[4] = (__bf16)v1[0]; r[5] = (__bf16)v1[1];
    r[6] = (__bf16)v1[2]; r[7] = (__bf16)v1[3];
    return r;
}

__global__ __launch_bounds__(256, 2)
void edge_mlp(const float* __restrict__ gsrc,
              const float* __restrict__ gdst,
              const float* __restrict__ gea,
              const float* __restrict__ gu,
              const int*   __restrict__ gbatch,
              const float* __restrict__ gw1,
              const float* __restrict__ gb1,
              const float* __restrict__ gw2,
              const float* __restrict__ gb2,
              float* __restrict__ gout)
{
    __shared__ __align__(16) __bf16 hl[64 * 128];   // h tile, XOR-swizzled

    const int tid  = threadIdx.x;
    const int lane = tid & 63;
    const int wid  = tid >> 6;     // wave 0..3 -> N-slice [wid*32, wid*32+32)
    const int l15  = lane & 15;
    const int g    = lane >> 4;    // 0..3
    const int wb   = wid * 32;

    // ---- stage weights into registers (B-fragments), once per block ----
    // B layout (16x16x32): lane holds B[k = ks*32 + g*8 + j][col = l15-based]
    bf16x8 w1f[2][4], w2f[2][4];
    float  b1v[2], b2v[2];
#pragma unroll
    for (int n = 0; n < 2; ++n) {
        const int col = wb + n * 16 + l15;
        b1v[n] = gb1[col];
        b2v[n] = gb2[col];
#pragma unroll
        for (int ks = 0; ks < 4; ++ks) {
            bf16x8 t1, t2;
#pragma unroll
            for (int j = 0; j < 8; ++j) {
                const int k = ks * 32 + g * 8 + j;
                t1[j] = (__bf16)gw1[k * 128 + col];
                t2[j] = (__bf16)gw2[k * 128 + col];
            }
            w1f[n][ks] = t1;
            w2f[n][ks] = t2;
        }
    }

    for (int tile = blockIdx.x; tile < NUM_TILES; tile += gridDim.x) {
        const int e0 = tile * 64;

        // ---- load x into A-fragments (direct from global, fp32 -> bf16) ----
        // A layout: lane holds A[row = m*16 + l15][k = ks*32 + g*8 + j]
        // k-step == source array: 0:src 1:dest 2:ea 3:u[batch]
        bf16x8 a[4][4];
#pragma unroll
        for (int m = 0; m < 4; ++m) {
            const int e = e0 + m * 16 + l15;
            const size_t off = (size_t)e * 32 + g * 8;
            a[m][0] = cvt8(gsrc + off);
            a[m][1] = cvt8(gdst + off);
            a[m][2] = cvt8(gea + off);
            const int bi = gbatch[e];
            a[m][3] = cvt8(gu + (size_t)bi * 32 + g * 8);
        }

        // ---- GEMM1: h = relu(x @ W1 + b1) ----
        f32x4 acc[4][2];
#pragma unroll
        for (int m = 0; m < 4; ++m)
#pragma unroll
            for (int n = 0; n < 2; ++n)
                acc[m][n] = (f32x4){b1v[n], b1v[n], b1v[n], b1v[n]};
#pragma unroll
        for (int ks = 0; ks < 4; ++ks)
#pragma unroll
            for (int m = 0; m < 4; ++m)
#pragma unroll
                for (int n = 0; n < 2; ++n)
                    acc[m][n] = __builtin_amdgcn_mfma_f32_16x16x32_bf16(
                        a[m][ks], w1f[n][ks], acc[m][n], 0, 0, 0);

        // ---- ReLU + write h to LDS (swizzled: col ^ ((row&7)<<3)) ----
        // C layout: row = m*16 + g*4 + r, col = wb + n*16 + l15
#pragma unroll
        for (int m = 0; m < 4; ++m)
#pragma unroll
            for (int n = 0; n < 2; ++n)
#pragma unroll
                for (int r = 0; r < 4; ++r) {
                    const int row = m * 16 + g * 4 + r;
                    const int col = wb + n * 16 + l15;
                    float v = acc[m][n][r];
                    v = v > 0.f ? v : 0.f;
                    hl[row * 128 + (col ^ ((row & 7) << 3))] = (__bf16)v;
                }
        __syncthreads();

        // ---- GEMM2: out = h @ W2 + b2 ----
        f32x4 acc2[4][2];
#pragma unroll
        for (int m = 0; m < 4; ++m)
#pragma unroll
            for (int n = 0; n < 2; ++n)
                acc2[m][n] = (f32x4){b2v[n], b2v[n], b2v[n], b2v[n]};
#pragma unroll
        for (int ks = 0; ks < 4; ++ks) {
            bf16x8 a2[4];
#pragma unroll
            for (int m = 0; m < 4; ++m) {
                const int row = m * 16 + l15;
                const int kb  = ks * 32 + g * 8;
                a2[m] = *(const bf16x8*)&hl[row * 128 + (kb ^ ((row & 7) << 3))];
            }
#pragma unroll
            for (int m = 0; m < 4; ++m)
#pragma unroll
                for (int n = 0; n < 2; ++n)
                    acc2[m][n] = __builtin_amdgcn_mfma_f32_16x16x32_bf16(
                        a2[m], w2f[n][ks], acc2[m][n], 0, 0, 0);
        }
        __syncthreads();   // hl reused next tile

        // ---- residual add + store ----
        // wave wid owns cols [wb, wb+32): array is wave-uniform
#pragma unroll
        for (int m = 0; m < 4; ++m) {
#pragma unroll
            for (int n = 0; n < 2; ++n) {
#pragma unroll
                for (int r = 0; r < 4; ++r) {
                    const int row = m * 16 + g * 4 + r;
                    const int e = e0 + row;
                    const int c = n * 16 + l15;    // 0..31 within array
                    float xv;
                    if (wid == 0)      xv = gsrc[(size_t)e * 32 + c];
                    else if (wid == 1) xv = gdst[(size_t)e * 32 + c];
                    else if (wid == 2) xv = gea[(size_t)e * 32 + c];
                    else               xv = gu[(size_t)gbatch[e] * 32 + c];
                    gout[(size_t)e * 128 + wb + c] = acc2[m][n][r] + xv;
                }
            }
        }
    }
}

extern "C" void kernel_launch(void* const* d_in, const int* in_sizes, int n_in,
                              void* d_out, int out_size, void* d_ws, size_t ws_size,
                              hipStream_t stream) {
    const float* src = (const float*)d_in[0];
    const float* dst = (const float*)d_in[1];
    const float* ea  = (const float*)d_in[2];
    const float* u   = (const float*)d_in[3];
    const int*   bt  = (const int*)d_in[4];
    const float* w1  = (const float*)d_in[5];
    const float* b1  = (const float*)d_in[6];
    const float* w2  = (const float*)d_in[7];
    const float* b2  = (const float*)d_in[8];
    float* out = (float*)d_out;

    edge_mlp<<<2048, 256, 0, stream>>>(src, dst, ea, u, bt, w1, b1, w2, b2, out);
}

// Round 2
// 179.901 us; speedup vs baseline: 2.8725x; 2.8725x over previous
//
#include <hip/hip_runtime.h>

// EdgeModel: out = relu(x@W1+b1)@W2 + b2 + x, x = [src|dest|ea|u[batch]] per edge.
// E=1e6, all dims 128. bf16 MFMA 16x16x32, fp32 accum.
// Structure: 64-edge tile/block, 4 waves N-split. x staged to LDS (bf16,
// XOR-swizzled), register-prefetched one tile ahead; residual read from LDS.

#define E_TOTAL   1000000
#define TILE_M    64
#define NUM_TILES (E_TOTAL / TILE_M)   // 15625, exact
#define GRID      2048

typedef __attribute__((ext_vector_type(8))) __bf16 bf16x8;
typedef __attribute__((ext_vector_type(4))) float  f32x4;

__device__ inline bf16x8 pack8(f32x4 v0, f32x4 v1) {
    bf16x8 r;
    r[0] = (__bf16)v0[0]; r[1] = (__bf16)v0[1];
    r[2] = (__bf16)v0[2]; r[3] = (__bf16)v0[3];
    r[4] = (__bf16)v1[0]; r[5] = (__bf16)v1[1];
    r[6] = (__bf16)v1[2]; r[7] = (__bf16)v1[3];
    return r;
}

// swizzled bf16 index: row-major [64][128] bf16, 16 groups of 8 bf16 per row,
// group XOR'd with (row&15) -> all b128 reads conflict-free at the b128 floor.
__device__ inline int swz(int row, int group) {
    return (row * 16 + (group ^ (row & 15))) * 8;
}

__global__ __launch_bounds__(256, 2)
void edge_mlp(const float* __restrict__ gsrc,
              const float* __restrict__ gdst,
              const float* __restrict__ gea,
              const float* __restrict__ gu,
              const int*   __restrict__ gbatch,
              const float* __restrict__ gw1,
              const float* __restrict__ gb1,
              const float* __restrict__ gw2,
              const float* __restrict__ gb2,
              float* __restrict__ gout)
{
    __shared__ __align__(16) __bf16 xs[TILE_M * 128];   // x tile (bf16, swizzled)
    __shared__ __align__(16) __bf16 hl[TILE_M * 128];   // h tile (bf16, swizzled)

    const int tid  = threadIdx.x;
    const int lane = tid & 63;
    const int wid  = tid >> 6;
    const int l15  = lane & 15;
    const int g    = lane >> 4;
    const int wb   = wid * 32;

    // ---- weights -> registers (B-fragments), once per block ----
    bf16x8 w1f[2][4], w2f[2][4];
    float  b1v[2], b2v[2];
#pragma unroll
    for (int n = 0; n < 2; ++n) {
        const int col = wb + n * 16 + l15;
        b1v[n] = gb1[col];
        b2v[n] = gb2[col];
#pragma unroll
        for (int ks = 0; ks < 4; ++ks) {
            bf16x8 t1, t2;
#pragma unroll
            for (int j = 0; j < 8; ++j) {
                const int k = ks * 32 + g * 8 + j;
                t1[j] = (__bf16)gw1[k * 128 + col];
                t2[j] = (__bf16)gw2[k * 128 + col];
            }
            w1f[n][ks] = t1;
            w2f[n][ks] = t2;
        }
    }

    // ---- staging geometry: thread t owns row=t>>2, 8-float chunk sub=t&3 of
    //      each of the 4 source arrays (fully coalesced dwordx4 loads) ----
    const int srow = tid >> 2;
    const int ssub = tid & 3;

    f32x4 pre[4][2];   // prefetched x rows (fp32), one tile ahead

    auto load_pre = [&](int t) {
        const int e = t * TILE_M + srow;
        // batch first: only its vmcnt gates the dependent u-gather
        const int bi = gbatch[e];
        const float* p0 = gsrc + (size_t)e * 32 + ssub * 8;
        const float* p1 = gdst + (size_t)e * 32 + ssub * 8;
        const float* p2 = gea  + (size_t)e * 32 + ssub * 8;
        pre[0][0] = *(const f32x4*)p0; pre[0][1] = *(const f32x4*)(p0 + 4);
        pre[1][0] = *(const f32x4*)p1; pre[1][1] = *(const f32x4*)(p1 + 4);
        pre[2][0] = *(const f32x4*)p2; pre[2][1] = *(const f32x4*)(p2 + 4);
        const float* p3 = gu + (size_t)bi * 32 + ssub * 8;
        pre[3][0] = *(const f32x4*)p3; pre[3][1] = *(const f32x4*)(p3 + 4);
    };

    int tile = blockIdx.x;
    load_pre(tile);

    while (true) {
        // ---- stage x tile into LDS (bf16, swizzled) ----
#pragma unroll
        for (int p = 0; p < 4; ++p) {
            *(bf16x8*)&xs[swz(srow, p * 4 + ssub)] = pack8(pre[p][0], pre[p][1]);
        }
        __syncthreads();

        // ---- prefetch next tile while computing this one ----
        const int  nxt  = tile + GRID;
        const bool have = nxt < NUM_TILES;
        if (have) load_pre(nxt);

        const int e0 = tile * TILE_M;

        // ---- GEMM1: h = relu(x @ W1 + b1) ----
        f32x4 acc[4][2];
#pragma unroll
        for (int m = 0; m < 4; ++m)
#pragma unroll
            for (int n = 0; n < 2; ++n)
                acc[m][n] = (f32x4){b1v[n], b1v[n], b1v[n], b1v[n]};
#pragma unroll
        for (int ks = 0; ks < 4; ++ks) {
            bf16x8 a[4];
#pragma unroll
            for (int m = 0; m < 4; ++m)
                a[m] = *(const bf16x8*)&xs[swz(m * 16 + l15, (ks * 4 + g) ^ 0)];
            // note: swz already XORs with row&15 == l15
#pragma unroll
            for (int m = 0; m < 4; ++m)
#pragma unroll
                for (int n = 0; n < 2; ++n)
                    acc[m][n] = __builtin_amdgcn_mfma_f32_16x16x32_bf16(
                        a[m], w1f[n][ks], acc[m][n], 0, 0, 0);
        }

        // ---- ReLU + h -> LDS (C-layout scalar writes, swizzled) ----
#pragma unroll
        for (int m = 0; m < 4; ++m)
#pragma unroll
            for (int n = 0; n < 2; ++n)
#pragma unroll
                for (int r = 0; r < 4; ++r) {
                    const int row = m * 16 + g * 4 + r;
                    const int c   = wb + n * 16 + l15;
                    float v = acc[m][n][r];
                    v = v > 0.f ? v : 0.f;
                    hl[swz(row, c >> 3) + (c & 7)] = (__bf16)v;
                }
        __syncthreads();

        // ---- GEMM2: out = h @ W2 + b2 ----
        f32x4 acc2[4][2];
#pragma unroll
        for (int m = 0; m < 4; ++m)
#pragma unroll
            for (int n = 0; n < 2; ++n)
                acc2[m][n] = (f32x4){b2v[n], b2v[n], b2v[n], b2v[n]};
#pragma unroll
        for (int ks = 0; ks < 4; ++ks) {
            bf16x8 a2[4];
#pragma unroll
            for (int m = 0; m < 4; ++m)
                a2[m] = *(const bf16x8*)&hl[swz(m * 16 + l15, ks * 4 + g)];
#pragma unroll
            for (int m = 0; m < 4; ++m)
#pragma unroll
                for (int n = 0; n < 2; ++n)
                    acc2[m][n] = __builtin_amdgcn_mfma_f32_16x16x32_bf16(
                        a2[m], w2f[n][ks], acc2[m][n], 0, 0, 0);
        }

        // ---- epilogue: + residual x (from LDS) -> global ----
#pragma unroll
        for (int m = 0; m < 4; ++m)
#pragma unroll
            for (int n = 0; n < 2; ++n)
#pragma unroll
                for (int r = 0; r < 4; ++r) {
                    const int row = m * 16 + g * 4 + r;
                    const int c   = wb + n * 16 + l15;
                    const float xv = (float)xs[swz(row, c >> 3) + (c & 7)];
                    gout[(size_t)(e0 + row) * 128 + c] = acc2[m][n][r] + xv;
                }
        __syncthreads();   // xs/hl reused next tile

        if (!have) break;
        tile = nxt;
    }
}

extern "C" void kernel_launch(void* const* d_in, const int* in_sizes, int n_in,
                              void* d_out, int out_size, void* d_ws, size_t ws_size,
                              hipStream_t stream) {
    const float* src = (const float*)d_in[0];
    const float* dst = (const float*)d_in[1];
    const float* ea  = (const float*)d_in[2];
    const float* u   = (const float*)d_in[3];
    const int*   bt  = (const int*)d_in[4];
    const float* w1  = (const float*)d_in[5];
    const float* b1  = (const float*)d_in[6];
    const float* w2  = (const float*)d_in[7];
    const float* b2  = (const float*)d_in[8];
    float* out = (float*)d_out;

    edge_mlp<<<GRID, 256, 0, stream>>>(src, dst, ea, u, bt, w1, b1, w2, b2, out);
}